// Round 7
// baseline (258.100 us; speedup 1.0000x reference)
//
#include <hip/hip_runtime.h>
#include <hip/hip_fp16.h>

// NCC loss, v13: fused kernel, LDS-pipe-targeted.
// v12 post-mortem: reg ring -> VGPR 112 -> 4 waves/SIMD = 2 blocks/CU,
// SAME occupancy as v10's LDS cap; +17% work from FCH=20; 141us.
// Pipe model (v10/v12 agree): stage B is LDS-read-pipe bound (~5-6k cy/CU
// per round: 512 columns x 9 rows x (b128+b32)); global-load latency
// exposed serially at round start on top.
// v13 = v10 geometry (FCH=40, 480 blocks, LDS ring, 2 blocks/CU) with:
//  (1) h-quad stage B on the stage-A-idle waves (tid 384..511): 12 tap rows
//      per 4 outputs (v9's verified slide) -> ~3x less LDS tap traffic;
//  (2) register prefetch of stage-A inputs for round r+1 issued right after
//      round r's ds_writes -> HBM latency paid at the barrier, not serially.
// Sync structure unchanged from the passing v10/v12 (2 syncthreads/round).
#define ND 2
#define DD 160
#define HH 192
#define WW 160
#define HW (HH * WW)
#define DHW (DD * HH * WW)

constexpr int TW  = 32;            // tile width  (outputs)
constexpr int TH  = 16;            // tile height (outputs) -> 512 columns
constexpr int HLO = TH + 8;        // 24 rows incl. H halo
constexpr int FCH = 40;            // d outputs per block
constexpr int NCH = DD / FCH;      // 4 chunks
constexpr int NSL = FCH + 8;       // 48 slices streamed
constexpr int NR  = NSL / 2;       // 24 rounds, 2 slices each

struct alignas(8) h4 { __half2 lo, hi; };

__device__ __forceinline__ void slide4(const float x[12], float S[4]) {
    float f = ((x[0] + x[1]) + (x[2] + x[3]))
            + ((x[4] + x[5]) + (x[6] + x[7])) + x[8];
    S[0] = f;
    f += x[9]  - x[0]; S[1] = f;
    f += x[10] - x[1]; S[2] = f;
    f += x[11] - x[2]; S[3] = f;
}

__global__ __launch_bounds__(512)
void ncc_fused3(const float* __restrict__ I, const float* __restrict__ J,
                float* __restrict__ outp)
{
    // stage-A output: centered W-sums of (I,J,II,JJ) + IJ, 2 slices
    __shared__ float4 sws[2][HLO][TW + 1];          // 25,344 B
    __shared__ float  sw4[2][HLO][TW + 1];          //  6,336 B
    // D-ring: last 9 slices' centered HW-sums, fp16 (proven ws format)
    __shared__ h4     ring4[9][512];                // 36,864 B
    __shared__ __half ring1[9][512];                //  9,216 B
    __shared__ float  wred[8];

    const int tid = threadIdx.x;
    const int w0  = blockIdx.x * TW;                // 0..128
    const int h0  = blockIdx.y * TH;                // 0..176
    const int z   = blockIdx.z;                     // 0..7
    const int n   = z >> 2;
    const int d0  = (z & 3) * FCH;

    // ---- stage-A role: threads 0..383 = 2 slices x 24 rows x 8 groups ----
    const bool ajob = (tid < 384);
    const int  sl   = tid / 192;                    // slice-of-round (0/1)
    const int  rj   = tid - sl * 192;
    const int  arow = rj >> 3;                      // 0..23
    const int  awg  = rj & 7;                       // 0..7
    const int  agh  = h0 + arow - 4;
    const bool ahok = (agh >= 0) && (agh < HH);
    const int  agws = w0 + awg * 4 - 4;

    // ---- stage-B role: threads 384..511, h-quad per thread ----
    const bool bjob = (tid >= 384);
    const int  tid2 = tid - 384;                    // 0..127
    const int  hq   = (tid2 >> 5) * 4;              // 0,4,8,12
    const int  ow   = tid2 & 31;                    // 0..31
    float cHW[4];
    #pragma unroll
    for (int k = 0; k < 4; ++k) {
        const int hg = h0 + hq + k, wg = w0 + ow;
        const float cWv = (float)(min(wg + 4, WW - 1) - max(wg - 4, 0) + 1);
        const float cHv = (float)(min(hg + 4, HH - 1) - max(hg - 4, 0) + 1);
        cHW[k] = cWv * cHv;
    }
    const int colbase = hq * 32 + ow;               // + 32*k per output

    // zero the ring (each thread zeroes column `tid`; consumers differ ->
    // one barrier before first use)
    {
        h4 zz; zz.lo = __floats2half2_rn(0.f, 0.f); zz.hi = zz.lo;
        const __half z1 = __float2half(0.f);
        #pragma unroll
        for (int q = 0; q < 9; ++q) { ring4[q][tid] = zz; ring1[q][tid] = z1; }
    }
    __syncthreads();

    float run[4][5];
    #pragma unroll
    for (int k = 0; k < 4; ++k)
        #pragma unroll
        for (int p = 0; p < 5; ++p) run[k][p] = 0.f;
    float acc = 0.f;
    const float inv = 1.0f / 729.0f;

    // prefetch registers (centered, zero-filled at boundaries)
    float pa[12], pb[12];
    auto load_ab = [&](int rrt) {
        const int dd  = d0 - 4 + 2 * rrt + sl;
        const bool dok = (dd >= 0) && (dd < DD);
        const int rbase = (n * DD + dd) * HW + agh * WW;
        #pragma unroll
        for (int c = 0; c < 3; ++c) {
            const int gw = agws + 4 * c;
            float4 va = make_float4(0.f, 0.f, 0.f, 0.f), vb = va;
            if (dok && ahok && gw >= 0 && gw < WW) {
                va = *(const float4*)(I + rbase + gw);
                vb = *(const float4*)(J + rbase + gw);
                va.x -= 0.5f; va.y -= 0.5f; va.z -= 0.5f; va.w -= 0.5f;
                vb.x -= 0.5f; vb.y -= 0.5f; vb.z -= 0.5f; vb.w -= 0.5f;
            }
            *(float4*)&pa[4 * c] = va;
            *(float4*)&pb[4 * c] = vb;
        }
    };
    if (ajob) load_ab(0);

    #pragma unroll 1
    for (int g = 0; g < 3; ++g) {                   // 3 x 9 = 27 >= NR
        #pragma unroll
        for (int r = 0; r < 9; ++r) {
            const int rr = g * 9 + r;
            if (rr < NR) {
                const int s0  = 2 * rr;
                const int dd0 = d0 - 4 + s0;
                // ---- stage A: consume prefetched regs, then prefetch next ----
                if (ajob) {
                    const int dd = dd0 + sl;
                    if (dd >= 0 && dd < DD) {
                        float S0[4], S1[4], S2[4], S3[4], S4[4], f[12];
                        slide4(pa, S0);
                        slide4(pb, S1);
                        #pragma unroll
                        for (int i = 0; i < 12; ++i) f[i] = pa[i] * pa[i];
                        slide4(f, S2);
                        #pragma unroll
                        for (int i = 0; i < 12; ++i) f[i] = pb[i] * pb[i];
                        slide4(f, S3);
                        #pragma unroll
                        for (int i = 0; i < 12; ++i) f[i] = pa[i] * pb[i];
                        slide4(f, S4);
                        #pragma unroll
                        for (int t = 0; t < 4; ++t) {
                            sws[sl][arow][awg * 4 + t] =
                                make_float4(S0[t], S1[t], S2[t], S3[t]);
                            sw4[sl][arow][awg * 4 + t] = S4[t];
                        }
                    }
                    if (rr + 1 < NR) load_ab(rr + 1);   // fly during stage B
                }
                __syncthreads();
                // ---- stage B: h-quad taps (12 rows / 4 outputs) + ring + cc ----
                if (bjob) {
                    #pragma unroll
                    for (int half = 0; half < 2; ++half) {
                        const int s   = s0 + half;
                        const int ddx = dd0 + half;
                        float t0=0.f,t1=0.f,t2=0.f,t3=0.f,t4=0.f;
                        float u0=0.f,u1=0.f,u2=0.f,u3=0.f,u4=0.f;
                        float v0=0.f,v1=0.f,v2=0.f,v3=0.f,v4=0.f;
                        float x0=0.f,x1=0.f,x2=0.f,x3=0.f,x4=0.f;
                        if (ddx >= 0 && ddx < DD) {
                            float a0x,a0y,a0z,a0w,a04;   // row hq
                            float a1x,a1y,a1z,a1w,a14;   // row hq+1
                            float a2x,a2y,a2z,a2w,a24;   // row hq+2
                            {
                                const float4 v = sws[half][hq][ow];
                                a0x=v.x; a0y=v.y; a0z=v.z; a0w=v.w;
                                a04 = sw4[half][hq][ow];
                                t0=a0x; t1=a0y; t2=a0z; t3=a0w; t4=a04;
                            }
                            {
                                const float4 v = sws[half][hq+1][ow];
                                a1x=v.x; a1y=v.y; a1z=v.z; a1w=v.w;
                                a14 = sw4[half][hq+1][ow];
                                t0+=a1x; t1+=a1y; t2+=a1z; t3+=a1w; t4+=a14;
                            }
                            {
                                const float4 v = sws[half][hq+2][ow];
                                a2x=v.x; a2y=v.y; a2z=v.z; a2w=v.w;
                                a24 = sw4[half][hq+2][ow];
                                t0+=a2x; t1+=a2y; t2+=a2z; t3+=a2w; t4+=a24;
                            }
                            #pragma unroll
                            for (int q = 3; q < 9; ++q) {
                                const float4 v = sws[half][hq+q][ow];
                                t0+=v.x; t1+=v.y; t2+=v.z; t3+=v.w;
                                t4+=sw4[half][hq+q][ow];
                            }
                            {
                                const float4 v = sws[half][hq+9][ow];
                                u0=t0+v.x-a0x; u1=t1+v.y-a0y; u2=t2+v.z-a0z;
                                u3=t3+v.w-a0w; u4=t4+sw4[half][hq+9][ow]-a04;
                            }
                            {
                                const float4 v = sws[half][hq+10][ow];
                                v0=u0+v.x-a1x; v1=u1+v.y-a1y; v2=u2+v.z-a1z;
                                v3=u3+v.w-a1w; v4=u4+sw4[half][hq+10][ow]-a14;
                            }
                            {
                                const float4 v = sws[half][hq+11][ow];
                                x0=v0+v.x-a2x; x1=v1+v.y-a2y; x2=v2+v.z-a2z;
                                x3=v3+v.w-a2w; x4=v4+sw4[half][hq+11][ow]-a24;
                            }
                        }
                        const int jj = (2 * r + half) % 9;  // compile-time
                        const float cD =
                            (float)(min((d0 + s - 8) + 4, DD - 1) -
                                    max((d0 + s - 8) - 4, 0) + 1);
                        #define DO_OUT(K, B0, B1, B2, B3, B4)                  \
                        {                                                      \
                            const int col = colbase + 32 * (K);                \
                            h4 nh;                                             \
                            nh.lo = __floats2half2_rn(B0, B1);                 \
                            nh.hi = __floats2half2_rn(B2, B3);                 \
                            const __half n4h = __float2half(B4);               \
                            const h4     po = ring4[jj][col];                  \
                            const __half p4 = ring1[jj][col];                  \
                            run[K][0] += __half2float(nh.lo.x) - __half2float(po.lo.x); \
                            run[K][1] += __half2float(nh.lo.y) - __half2float(po.lo.y); \
                            run[K][2] += __half2float(nh.hi.x) - __half2float(po.hi.x); \
                            run[K][3] += __half2float(nh.hi.y) - __half2float(po.hi.y); \
                            run[K][4] += __half2float(n4h)     - __half2float(p4);      \
                            ring4[jj][col] = nh;                               \
                            ring1[jj][col] = n4h;                              \
                            if (s >= 8) {                                      \
                                const float cnt = cHW[K] * cD;                 \
                                const float Is = run[K][0] + 0.5f * cnt;       \
                                const float Js = run[K][1] + 0.5f * cnt;       \
                                const float I2 = run[K][2] + run[K][0] + 0.25f * cnt; \
                                const float J2 = run[K][3] + run[K][1] + 0.25f * cnt; \
                                const float IJ = run[K][4] +                   \
                                    0.5f * (run[K][0] + run[K][1]) + 0.25f * cnt; \
                                const float uI = Is * inv, uJ = Js * inv;      \
                                const float cross = IJ - uI * Js;              \
                                const float Iv = fmaxf(I2 - uI * Is, 1e-5f);   \
                                const float Jv = fmaxf(J2 - uJ * Js, 1e-5f);   \
                                acc += cross * cross / (Iv * Jv + 1e-5f);      \
                            }                                                  \
                        }
                        DO_OUT(0, t0, t1, t2, t3, t4)
                        DO_OUT(1, u0, u1, u2, u3, u4)
                        DO_OUT(2, v0, v1, v2, v3, v4)
                        DO_OUT(3, x0, x1, x2, x3, x4)
                        #undef DO_OUT
                    }
                }
                __syncthreads();
            }
        }
    }

    // ---- block reduction, one fp32 atomic per block ----
    #pragma unroll
    for (int off = 32; off > 0; off >>= 1)
        acc += __shfl_down(acc, off, 64);
    const int lane = tid & 63, wid = tid >> 6;
    if (lane == 0) wred[wid] = acc;
    __syncthreads();
    if (tid == 0) {
        float ssum = 0.f;
        #pragma unroll
        for (int i = 0; i < 8; ++i) ssum += wred[i];
        atomicAdd(outp, -ssum);
    }
}

extern "C" void kernel_launch(void* const* d_in, const int* in_sizes, int n_in,
                              void* d_out, int out_size, void* d_ws, size_t ws_size,
                              hipStream_t stream)
{
    const float* I = (const float*)d_in[0];   // y_true
    const float* J = (const float*)d_in[1];   // y_pred
    float* out = (float*)d_out;

    hipMemsetAsync(out, 0, sizeof(float), stream);
    dim3 grid(WW / TW, HH / TH, ND * NCH);    // 5 x 12 x 8 = 480 blocks
    ncc_fused3<<<grid, 512, 0, stream>>>(I, J, out);
}

// Round 8
// 184.284 us; speedup vs baseline: 1.4006x; 1.4006x over previous
//
#include <hip/hip_runtime.h>
#include <hip/hip_fp16.h>

// NCC loss, v14: fused kernel, LDS-instruction-count attack.
// v13 post-mortem: role-split stage B onto 128 threads made the LDS phase a
// 2-wave serial section (VALU 14%, 254us). Lesson: cut ops/thread only if
// issuing-thread count stays up.
// v10 pipe model: per block-round LDS ~5.8k cy (18 taps + 4 ring ops x 8
// waves) + VALU ~4.6k cy vs 9.3k measured -> dual-pipe issue-bound.
// v14 = v10 structure (all-thread stage B, 1 output/thread, LDS ring,
// FCH=40, 2 barriers/round) with:
//  (1) sws rows packed 8x fp16 (16B): {I,J},{II,JJ},{IJ,0} -> taps are
//      9 b128 (was 9 b128 + 9 b32), summed with v_pk_add_f16 (3/row).
//      Ring entry = the fp16 sums directly; ring/run algebra unchanged.
//  (2) register prefetch of next round's stage-A inputs (proven in v13).
// LDS 71.5KB -> 2 blocks/CU (as v10). VGPR ~75-90, no launch_bounds squeeze.
#define ND 2
#define DD 160
#define HH 192
#define WW 160
#define HW (HH * WW)
#define DHW (DD * HH * WW)

constexpr int TW  = 32;            // tile width  (outputs)
constexpr int TH  = 16;            // tile height (outputs) -> 512 columns
constexpr int HLO = TH + 8;        // 24 rows incl. H halo
constexpr int FCH = 40;            // d outputs per block
constexpr int NCH = DD / FCH;      // 4 chunks
constexpr int NSL = FCH + 8;       // 48 slices streamed
constexpr int NR  = NSL / 2;       // 24 rounds, 2 slices each

struct alignas(8)  h4 { __half2 lo, hi; };
struct alignas(16) h8 { __half2 a, b, c, d; };

__device__ __forceinline__ void slide4(const float x[12], float S[4]) {
    float f = ((x[0] + x[1]) + (x[2] + x[3]))
            + ((x[4] + x[5]) + (x[6] + x[7])) + x[8];
    S[0] = f;
    f += x[9]  - x[0]; S[1] = f;
    f += x[10] - x[1]; S[2] = f;
    f += x[11] - x[2]; S[3] = f;
}

__global__ __launch_bounds__(512)
void ncc_fused4(const float* __restrict__ I, const float* __restrict__ J,
                float* __restrict__ outp)
{
    // stage-A output: centered W-sums, fp16-packed {I,J},{II,JJ},{IJ,0},pad
    __shared__ h8     sws[2][HLO][TW + 1];          // 25,344 B
    // D-ring: last 9 slices' centered HW-sums, fp16 (proven format)
    __shared__ h4     ring4[9][512];                // 36,864 B
    __shared__ __half ring1[9][512];                //  9,216 B
    __shared__ float  wred[8];

    const int tid = threadIdx.x;
    const int w0  = blockIdx.x * TW;                // 0..128
    const int h0  = blockIdx.y * TH;                // 0..176
    const int z   = blockIdx.z;                     // 0..7
    const int n   = z >> 2;
    const int d0  = (z & 3) * FCH;

    // ---- stage-A role: 384 jobs = 2 slices x 24 rows x 8 groups ----
    const bool ajob = (tid < 384);
    const int  sl   = tid / 192;                    // slice-of-round (0/1)
    const int  rj   = tid - sl * 192;
    const int  arow = rj >> 3;                      // 0..23
    const int  awg  = rj & 7;                       // 0..7
    const int  agh  = h0 + arow - 4;
    const bool ahok = (agh >= 0) && (agh < HH);
    const int  agws = w0 + awg * 4 - 4;

    // ---- stage-B role: one (h,w) column per thread (all 512) ----
    const int oh = tid >> 5;                        // 0..15
    const int ow = tid & 31;                        // 0..31
    const int h  = h0 + oh, w = w0 + ow;
    const float cW  = (float)(min(w + 4, WW - 1) - max(w - 4, 0) + 1);
    const float cH  = (float)(min(h + 4, HH - 1) - max(h - 4, 0) + 1);
    const float cHW = cW * cH;

    // zero this thread's ring slots (self-owned column, no barrier needed)
    {
        h4 zz; zz.lo = __floats2half2_rn(0.f, 0.f); zz.hi = zz.lo;
        const __half z1 = __float2half(0.f);
        #pragma unroll
        for (int q = 0; q < 9; ++q) { ring4[q][tid] = zz; ring1[q][tid] = z1; }
    }

    float run0 = 0.f, run1 = 0.f, run2 = 0.f, run3 = 0.f, run4 = 0.f;
    float acc = 0.f;
    const float inv = 1.0f / 729.0f;

    // prefetch registers (centered, zero-filled at boundaries)
    float pa[12], pb[12];
    auto load_ab = [&](int rrt) {
        const int dd  = d0 - 4 + 2 * rrt + sl;
        const bool dok = (dd >= 0) && (dd < DD);
        const int rbase = (n * DD + dd) * HW + agh * WW;
        #pragma unroll
        for (int c = 0; c < 3; ++c) {
            const int gw = agws + 4 * c;
            float4 va = make_float4(0.f, 0.f, 0.f, 0.f), vb = va;
            if (dok && ahok && gw >= 0 && gw < WW) {
                va = *(const float4*)(I + rbase + gw);
                vb = *(const float4*)(J + rbase + gw);
                va.x -= 0.5f; va.y -= 0.5f; va.z -= 0.5f; va.w -= 0.5f;
                vb.x -= 0.5f; vb.y -= 0.5f; vb.z -= 0.5f; vb.w -= 0.5f;
            }
            *(float4*)&pa[4 * c] = va;
            *(float4*)&pb[4 * c] = vb;
        }
    };
    if (ajob) load_ab(0);

    #pragma unroll 1
    for (int g = 0; g < 3; ++g) {                   // 3 x 9 = 27 >= NR
        #pragma unroll
        for (int r = 0; r < 9; ++r) {
            const int rr = g * 9 + r;
            if (rr < NR) {
                const int s0  = 2 * rr;
                const int dd0 = d0 - 4 + s0;
                // ---- stage A: consume prefetched regs, pack fp16, store ----
                if (ajob) {
                    const int dd = dd0 + sl;
                    if (dd >= 0 && dd < DD) {
                        float S0[4], S1[4], S2[4], S3[4], S4[4], f[12];
                        slide4(pa, S0);
                        slide4(pb, S1);
                        #pragma unroll
                        for (int i = 0; i < 12; ++i) f[i] = pa[i] * pa[i];
                        slide4(f, S2);
                        #pragma unroll
                        for (int i = 0; i < 12; ++i) f[i] = pb[i] * pb[i];
                        slide4(f, S3);
                        #pragma unroll
                        for (int i = 0; i < 12; ++i) f[i] = pa[i] * pb[i];
                        slide4(f, S4);
                        #pragma unroll
                        for (int t = 0; t < 4; ++t) {
                            h8 e;
                            e.a = __floats2half2_rn(S0[t], S1[t]);
                            e.b = __floats2half2_rn(S2[t], S3[t]);
                            e.c = __floats2half2_rn(S4[t], 0.f);
                            e.d = __floats2half2_rn(0.f, 0.f);
                            sws[sl][arow][awg * 4 + t] = e;
                        }
                    }
                    if (rr + 1 < NR) load_ab(rr + 1);   // fly during stage B
                }
                __syncthreads();
                // ---- stage B: 9 b128 taps, pk_add_f16 sums, ring + cc ----
                #pragma unroll
                for (int half = 0; half < 2; ++half) {
                    const int s   = s0 + half;
                    const int ddx = dd0 + half;
                    __half2 a01 = __floats2half2_rn(0.f, 0.f);
                    __half2 a23 = a01, a4 = a01;
                    if (ddx >= 0 && ddx < DD) {
                        #pragma unroll
                        for (int q = 0; q < 9; ++q) {
                            const h8 v = sws[half][oh + q][ow];
                            a01 = __hadd2(a01, v.a);
                            a23 = __hadd2(a23, v.b);
                            a4  = __hadd2(a4,  v.c);
                        }
                    }
                    h4 nh; nh.lo = a01; nh.hi = a23;
                    const __half n4h = __low2half(a4);
                    const int jj = (2 * r + half) % 9;   // compile-time const
                    const h4     po = ring4[jj][tid];
                    const __half p4 = ring1[jj][tid];
                    run0 += __low2float(nh.lo)  - __low2float(po.lo);
                    run1 += __high2float(nh.lo) - __high2float(po.lo);
                    run2 += __low2float(nh.hi)  - __low2float(po.hi);
                    run3 += __high2float(nh.hi) - __high2float(po.hi);
                    run4 += __half2float(n4h)   - __half2float(p4);
                    ring4[jj][tid] = nh;
                    ring1[jj][tid] = n4h;
                    if (s >= 8) {
                        const int d = d0 + s - 8;
                        const float cD  = (float)(min(d + 4, DD - 1) - max(d - 4, 0) + 1);
                        const float cnt = cHW * cD;
                        // reconstruct uncentered box sums (exact algebra)
                        const float Is = run0 + 0.5f * cnt;
                        const float Js = run1 + 0.5f * cnt;
                        const float I2 = run2 + run0 + 0.25f * cnt;
                        const float J2 = run3 + run1 + 0.25f * cnt;
                        const float IJ = run4 + 0.5f * (run0 + run1) + 0.25f * cnt;
                        const float uI = Is * inv, uJ = Js * inv;
                        const float cross = IJ - uI * Js;
                        const float Iv = fmaxf(I2 - uI * Is, 1e-5f);
                        const float Jv = fmaxf(J2 - uJ * Js, 1e-5f);
                        acc += cross * cross / (Iv * Jv + 1e-5f);
                    }
                }
                __syncthreads();
            }
        }
    }

    // ---- block reduction, one fp32 atomic per block ----
    #pragma unroll
    for (int off = 32; off > 0; off >>= 1)
        acc += __shfl_down(acc, off, 64);
    const int lane = tid & 63, wid = tid >> 6;
    if (lane == 0) wred[wid] = acc;
    __syncthreads();
    if (tid == 0) {
        float ssum = 0.f;
        #pragma unroll
        for (int i = 0; i < 8; ++i) ssum += wred[i];
        atomicAdd(outp, -ssum);
    }
}

extern "C" void kernel_launch(void* const* d_in, const int* in_sizes, int n_in,
                              void* d_out, int out_size, void* d_ws, size_t ws_size,
                              hipStream_t stream)
{
    const float* I = (const float*)d_in[0];   // y_true
    const float* J = (const float*)d_in[1];   // y_pred
    float* out = (float*)d_out;

    hipMemsetAsync(out, 0, sizeof(float), stream);
    dim3 grid(WW / TW, HH / TH, ND * NCH);    // 5 x 12 x 8 = 480 blocks
    ncc_fused4<<<grid, 512, 0, stream>>>(I, J, out);
}